// Round 3
// baseline (715.135 us; speedup 1.0000x reference)
//
#include <hip/hip_runtime.h>
#include <hip/hip_bf16.h>

#define BATCH 32
#define HW1 224

typedef __attribute__((ext_vector_type(8))) short short8;
typedef __attribute__((ext_vector_type(4))) float floatx4;

static __device__ __forceinline__ unsigned short f2bf(float f) {
    unsigned int u = __float_as_uint(f);
    unsigned int r = (u + 0x7fffu + ((u >> 16) & 1u)) >> 16;   // RNE
    return (unsigned short)r;
}

// ---------------------------------------------------------------------------
// Kernel A1: tiny MLP front (h1,h2), BN const folding, feat zero. One block.
// ---------------------------------------------------------------------------
__global__ __launch_bounds__(256) void gen_small(
    const float* __restrict__ w1, const float* __restrict__ b1,
    const float* __restrict__ w2, const float* __restrict__ b2,
    const float* __restrict__ wb, const float* __restrict__ bb,
    const float* __restrict__ conv2_b, const float* __restrict__ conv3_b,
    const float* __restrict__ bn1_g, const float* __restrict__ bn1_b,
    const float* __restrict__ bn1_m, const float* __restrict__ bn1_v,
    const float* __restrict__ bn2_g, const float* __restrict__ bn2_b,
    const float* __restrict__ bn2_m, const float* __restrict__ bn2_v,
    const float* __restrict__ bn3_g, const float* __restrict__ bn3_b,
    const float* __restrict__ bn3_m, const float* __restrict__ bn3_v,
    float* __restrict__ h2g,
    float* __restrict__ bn1_s, float* __restrict__ bn1_t,
    float* __restrict__ bn2_s, float* __restrict__ bn2_t,
    float* __restrict__ bn3_s, float* __restrict__ bn3_t,
    float* __restrict__ feat)
{
    __shared__ float h1[128];
    const int t = threadIdx.x;

    if (t < 128) {
        float s = b1[t] + w1[t*3+0] + w1[t*3+1] + w1[t*3+2];
        h1[t] = fmaxf(s, 0.f);
    }
    __syncthreads();
    {
        float s = b2[t];
        const float* wr = w2 + (size_t)t*128;
#pragma unroll 4
        for (int k = 0; k < 128; k += 4) {
            float4 wv = *(const float4*)(wr + k);
            s = fmaf(wv.x, h1[k  ], s);
            s = fmaf(wv.y, h1[k+1], s);
            s = fmaf(wv.z, h1[k+2], s);
            s = fmaf(wv.w, h1[k+3], s);
        }
        h2g[t] = fmaxf(s, 0.f);
    }
    if (t < 32) {
        float dynb = bb[t] + wb[t*3+0] + wb[t*3+1] + wb[t*3+2];
        float s = bn1_g[t] / sqrtf(bn1_v[t] + 1e-5f);
        bn1_s[t] = s;
        bn1_t[t] = (dynb - bn1_m[t]) * s + bn1_b[t];
    }
    if (t < 64) {
        float s = bn2_g[t] / sqrtf(bn2_v[t] + 1e-5f);
        bn2_s[t] = s;
        bn2_t[t] = (conv2_b[t] - bn2_m[t]) * s + bn2_b[t];
    }
    if (t < 128) {
        float s = bn3_g[t] / sqrtf(bn3_v[t] + 1e-5f);
        bn3_s[t] = s;
        bn3_t[t] = (conv3_b[t] - bn3_m[t]) * s + bn3_b[t];
    }
    for (int i = t; i < BATCH*128; i += 256) feat[i] = 0.f;
}

// ---------------------------------------------------------------------------
// Kernel A2: dyn_w = W3 @ h2 + b3 (wave-per-row, lane-split K=256) in blocks
// [0,216); conv2/conv3 weight repack to [tap][OC][IC] bf16 in blocks [216,576).
// ---------------------------------------------------------------------------
__global__ __launch_bounds__(256) void gen_dynw_repack(
    const float* __restrict__ w3, const float* __restrict__ b3,
    const float* __restrict__ h2g,
    const float* __restrict__ conv2_w, const float* __restrict__ conv3_w,
    float* __restrict__ dyn_w,
    unsigned short* __restrict__ wrep2, unsigned short* __restrict__ wrep3)
{
    __shared__ float h2s[256];
    const int blk = blockIdx.x;
    if (blk < 216) {
        h2s[threadIdx.x] = h2g[threadIdx.x];
        __syncthreads();
        const int wave = threadIdx.x >> 6, lane = threadIdx.x & 63;
        const int row = blk*4 + wave;
        float4 wv = *(const float4*)(w3 + (size_t)row*256 + lane*4);
        float4 hv = *(const float4*)&h2s[lane*4];
        float s = wv.x*hv.x + wv.y*hv.y + wv.z*hv.z + wv.w*hv.w;
#pragma unroll
        for (int m = 1; m < 64; m <<= 1) s += __shfl_xor(s, m);
        if (lane == 0) dyn_w[row] = s + b3[row];
    } else {
        const int i = (blk - 216)*256 + threadIdx.x;
        const int N2 = 9*64*32;   // 18432
        if (i < N2) {
            int t = i / (64*32); int rem = i - t*(64*32);
            int oc = rem >> 5, ic = rem & 31;
            wrep2[i] = f2bf(conv2_w[(oc*32 + ic)*9 + t]);
        } else {
            int j = i - N2;       // j < 9*128*64
            int t = j / (128*64); int rem = j - t*(128*64);
            int oc = rem >> 6, ic = rem & 63;
            wrep3[j] = f2bf(conv3_w[(oc*64 + ic)*9 + t]);
        }
    }
}

// ---------------------------------------------------------------------------
// Kernel B: conv1 (3->32, 224x224, pad1) + bn + relu + 2x2 maxpool.
// One block = 16x16 pooled tile x ALL 32 oc. Patch held in registers; taps
// looped with 8-oc x 4-position register accumulators (weights transposed
// [tap][oc] in LDS -> broadcast b128 reads). Output bf16 channel-last.
// ---------------------------------------------------------------------------
__global__ __launch_bounds__(256, 4) void conv1_pool(
    const float* __restrict__ x, const float* __restrict__ dw,
    const float* __restrict__ bn_s, const float* __restrict__ bn_t,
    unsigned short* __restrict__ act1)
{
    constexpr int PS = 36;   // even stride: float2 loads stay 8B aligned
    __shared__ __align__(16) float sp[3*34*PS];     // 14688 B
    __shared__ __align__(16) float swt[27*32];      // [tap][oc], 3456 B

    const int tid = threadIdx.x;
    const int bx = blockIdx.x, by = blockIdx.y, b = blockIdx.z;
    const int gx0 = bx*32 - 1, gy0 = by*32 - 1;
    const float* xb = x + (size_t)b * 3 * HW1 * HW1;

    for (int i = tid; i < 3*34*34; i += 256) {
        int ch = i / 1156; int rem = i - ch*1156;
        int r = rem / 34, c = rem - r*34;
        int gy = gy0 + r, gx = gx0 + c;
        float v = 0.f;
        if ((unsigned)gy < HW1 && (unsigned)gx < HW1)
            v = xb[(ch*HW1 + gy)*HW1 + gx];
        sp[(ch*34 + r)*PS + c] = v;
    }
    for (int i = tid; i < 27*32; i += 256) {
        int k = i >> 5, oc = i & 31;
        swt[i] = dw[oc*27 + k];
    }
    __syncthreads();

    const int tx = tid & 15, ty = tid >> 4;
    float p[3][4][4];
#pragma unroll
    for (int ch = 0; ch < 3; ++ch)
#pragma unroll
        for (int r = 0; r < 4; ++r) {
            const float* rp = &sp[(ch*34 + 2*ty + r)*PS + 2*tx];
            float2 a  = *(const float2*)rp;
            float2 bq = *(const float2*)(rp + 2);
            p[ch][r][0] = a.x;  p[ch][r][1] = a.y;
            p[ch][r][2] = bq.x; p[ch][r][3] = bq.y;
        }

    const int py = by*16 + ty, px = bx*16 + tx;
    unsigned short* dst = act1 + ((size_t)((b*112 + py)*112 + px))*32;

    for (int g = 0; g < 4; ++g) {            // 8 oc per group
        float acc[8][4];
#pragma unroll
        for (int o = 0; o < 8; ++o)
#pragma unroll
            for (int q = 0; q < 4; ++q) acc[o][q] = 0.f;

#pragma unroll
        for (int ch = 0; ch < 3; ++ch)
#pragma unroll
            for (int ky = 0; ky < 3; ++ky)
#pragma unroll
                for (int kx = 0; kx < 3; ++kx) {
                    const float* wp = &swt[(ch*9 + ky*3 + kx)*32 + g*8];
                    float4 w0 = *(const float4*)wp;
                    float4 w1 = *(const float4*)(wp + 4);
                    float wv[8] = {w0.x,w0.y,w0.z,w0.w,w1.x,w1.y,w1.z,w1.w};
                    float pv[4] = {p[ch][ky][kx],   p[ch][ky][kx+1],
                                   p[ch][ky+1][kx], p[ch][ky+1][kx+1]};
#pragma unroll
                    for (int o = 0; o < 8; ++o)
#pragma unroll
                        for (int q = 0; q < 4; ++q)
                            acc[o][q] = fmaf(wv[o], pv[q], acc[o][q]);
                }

        unsigned int pk[4];
#pragma unroll
        for (int o = 0; o < 8; ++o) {
            int oc = g*8 + o;
            float s = bn_s[oc], t = bn_t[oc];
            float m = fmaxf(fmaxf(fmaf(acc[o][0], s, t), fmaf(acc[o][1], s, t)),
                            fmaxf(fmaf(acc[o][2], s, t), fmaf(acc[o][3], s, t)));
            m = fmaxf(m, 0.f);
            unsigned short us = f2bf(m);
            if (o & 1) pk[o >> 1] |= ((unsigned int)us) << 16;
            else       pk[o >> 1]  = us;
        }
        *(uint4*)(dst + g*8) = *(uint4*)pk;
    }
}

// ---------------------------------------------------------------------------
// Kernel C: conv2 (32->64, 112x112) bf16 MFMA + bn + relu + 2x2 maxpool.
// ---------------------------------------------------------------------------
__global__ __launch_bounds__(256) void conv2_mfma(
    const unsigned short* __restrict__ act1,
    const unsigned short* __restrict__ wrep,
    const float* __restrict__ bn_s, const float* __restrict__ bn_t,
    unsigned short* __restrict__ act2)
{
    constexpr int IC = 32, OC = 64, H = 112;
    __shared__ __align__(16) short lds[4*18*18*8];   // [chunk][y][x][8ic]

    const int tid = threadIdx.x;
    const int b = blockIdx.z;
    const int cx0 = blockIdx.x*16, cy0 = blockIdx.y*16;
    const unsigned short* ab = act1 + (size_t)b*H*H*IC;

    for (int s = tid; s < 4*324; s += 256) {
        int ck = s / 324; int rem = s - ck*324;
        int y = rem / 18, xx = rem - y*18;
        int gy = cy0 - 1 + y, gx = cx0 - 1 + xx;
        uint4 v = {0,0,0,0};
        if ((unsigned)gy < H && (unsigned)gx < H)
            v = *(const uint4*)(ab + (size_t)(gy*H + gx)*IC + ck*8);
        *(uint4*)&lds[s*8] = v;
    }

    const int lane = tid & 63, wave = tid >> 6;
    const int n = lane & 15, quad = lane >> 4;
    const int oc0w = wave * 16;

    short8 afr[9];
#pragma unroll
    for (int t = 0; t < 9; ++t)
        afr[t] = *(const short8*)(wrep + (size_t)(t*OC + oc0w + n)*IC + quad*8);

    float4 sv = *(const float4*)(bn_s + oc0w + quad*4);
    float4 tv = *(const float4*)(bn_t + oc0w + quad*4);

    __syncthreads();

    for (int ry = 0; ry < 8; ++ry) {
        floatx4 acc0 = {0.f,0.f,0.f,0.f};
        floatx4 acc1 = {0.f,0.f,0.f,0.f};
        int y0 = 2*ry;
#pragma unroll
        for (int ky = 0; ky < 3; ++ky)
#pragma unroll
            for (int kx = 0; kx < 3; ++kx) {
                int t = ky*3 + kx;
                short8 b0 = *(const short8*)&lds[((quad*18 + y0+ky  )*18 + n+kx)*8];
                short8 b1 = *(const short8*)&lds[((quad*18 + y0+1+ky)*18 + n+kx)*8];
                acc0 = __builtin_amdgcn_mfma_f32_16x16x32_bf16(afr[t], b0, acc0, 0, 0, 0);
                acc1 = __builtin_amdgcn_mfma_f32_16x16x32_bf16(afr[t], b1, acc1, 0, 0, 0);
            }
        unsigned int pk[2];
        float sj[4] = {sv.x, sv.y, sv.z, sv.w};
        float tj[4] = {tv.x, tv.y, tv.z, tv.w};
#pragma unroll
        for (int j = 0; j < 4; ++j) {
            float va = fmaxf(fmaf(acc0[j], sj[j], tj[j]), 0.f);
            float vb = fmaxf(fmaf(acc1[j], sj[j], tj[j]), 0.f);
            float m  = fmaxf(va, vb);
            m = fmaxf(m, __shfl_xor(m, 1));
            unsigned short us = f2bf(m);
            if (j & 1) pk[j >> 1] |= ((unsigned int)us) << 16;
            else       pk[j >> 1]  = us;
        }
        if (!(n & 1)) {
            int py = (cy0 >> 1) + ry, px = (cx0 >> 1) + (n >> 1);
            unsigned short* dst = act2 + ((size_t)((b*56 + py)*56 + px))*OC + oc0w + quad*4;
            *(uint2*)dst = *(uint2*)pk;
        }
    }
}

// ---------------------------------------------------------------------------
// Kernel D: conv3 (64->128, 56x56) bf16 MFMA + bn + relu + spatial mean sum.
// ---------------------------------------------------------------------------
__global__ __launch_bounds__(256) void conv3_mfma(
    const unsigned short* __restrict__ act2,
    const unsigned short* __restrict__ wrep,
    const float* __restrict__ bn_s, const float* __restrict__ bn_t,
    float* __restrict__ feat)
{
    constexpr int IC = 64, OC = 128, H = 56;
    __shared__ __align__(16) short lds[8*18*18*8];

    const int tid = threadIdx.x;
    const int b = blockIdx.z >> 1, half = blockIdx.z & 1;
    const int cx0 = blockIdx.x*16, cy0 = blockIdx.y*16;
    const unsigned short* ab = act2 + (size_t)b*H*H*IC;

    for (int s = tid; s < 8*324; s += 256) {
        int ck = s / 324; int rem = s - ck*324;
        int y = rem / 18, xx = rem - y*18;
        int gy = cy0 - 1 + y, gx = cx0 - 1 + xx;
        uint4 v = {0,0,0,0};
        if ((unsigned)gy < H && (unsigned)gx < H)
            v = *(const uint4*)(ab + (size_t)(gy*H + gx)*IC + ck*8);
        *(uint4*)&lds[s*8] = v;
    }

    const int lane = tid & 63, wave = tid >> 6;
    const int n = lane & 15, quad = lane >> 4;
    const int oc0w = half*64 + wave*16;

    short8 afr[18];
#pragma unroll
    for (int t = 0; t < 9; ++t)
#pragma unroll
        for (int kc = 0; kc < 2; ++kc)
            afr[t*2 + kc] = *(const short8*)(wrep + (size_t)(t*OC + oc0w + n)*IC + kc*32 + quad*8);

    float4 sv = *(const float4*)(bn_s + oc0w + quad*4);
    float4 tv = *(const float4*)(bn_t + oc0w + quad*4);

    __syncthreads();

    float sum[4] = {0.f, 0.f, 0.f, 0.f};
    const bool vx = (cx0 + n) < H;
    const int ymax = (H - cy0) < 16 ? (H - cy0) : 16;
    float sj[4] = {sv.x, sv.y, sv.z, sv.w};
    float tj[4] = {tv.x, tv.y, tv.z, tv.w};

    for (int y = 0; y < ymax; ++y) {
        floatx4 acc0 = {0.f,0.f,0.f,0.f};
        floatx4 acc1 = {0.f,0.f,0.f,0.f};
#pragma unroll
        for (int ky = 0; ky < 3; ++ky)
#pragma unroll
            for (int kx = 0; kx < 3; ++kx) {
                int t = ky*3 + kx;
                short8 b0 = *(const short8*)&lds[(((0*4 + quad)*18 + y+ky)*18 + n+kx)*8];
                short8 b1 = *(const short8*)&lds[(((1*4 + quad)*18 + y+ky)*18 + n+kx)*8];
                acc0 = __builtin_amdgcn_mfma_f32_16x16x32_bf16(afr[t*2+0], b0, acc0, 0, 0, 0);
                acc1 = __builtin_amdgcn_mfma_f32_16x16x32_bf16(afr[t*2+1], b1, acc1, 0, 0, 0);
            }
        if (vx) {
#pragma unroll
            for (int j = 0; j < 4; ++j)
                sum[j] += fmaxf(fmaf(acc0[j] + acc1[j], sj[j], tj[j]), 0.f);
        }
    }
#pragma unroll
    for (int j = 0; j < 4; ++j) {
        sum[j] += __shfl_xor(sum[j], 1);
        sum[j] += __shfl_xor(sum[j], 2);
        sum[j] += __shfl_xor(sum[j], 4);
        sum[j] += __shfl_xor(sum[j], 8);
    }
    if (n == 0) {
#pragma unroll
        for (int j = 0; j < 4; ++j)
            atomicAdd(&feat[b*128 + oc0w + quad*4 + j], sum[j]);
    }
}

// ---------------------------------------------------------------------------
// Kernel E: FC head.
// ---------------------------------------------------------------------------
__global__ __launch_bounds__(256) void fc_kernel(
    const float* __restrict__ feat, const float* __restrict__ fc_w,
    const float* __restrict__ fc_b, float* __restrict__ out)
{
    int i = blockIdx.x * 256 + threadIdx.x;
    if (i >= BATCH*100) return;
    int b = i / 100, n = i - b*100;
    const float* f = feat + b*128;
    const float* w = fc_w + n*128;
    float s = 0.f;
#pragma unroll 4
    for (int k = 0; k < 128; ++k) s = fmaf(f[k], w[k], s);
    out[i] = s * (1.f/3136.f) + fc_b[n];
}

extern "C" void kernel_launch(void* const* d_in, const int* in_sizes, int n_in,
                              void* d_out, int out_size, void* d_ws, size_t ws_size,
                              hipStream_t stream)
{
    const float* x       = (const float*)d_in[0];
    const float* w1      = (const float*)d_in[1];
    const float* b1      = (const float*)d_in[2];
    const float* w2      = (const float*)d_in[3];
    const float* b2      = (const float*)d_in[4];
    const float* w3      = (const float*)d_in[5];
    const float* b3      = (const float*)d_in[6];
    const float* wb      = (const float*)d_in[7];
    const float* bb      = (const float*)d_in[8];
    const float* conv2_w = (const float*)d_in[9];
    const float* conv3_w = (const float*)d_in[11];
    const float* conv2_b = (const float*)d_in[10];
    const float* conv3_b = (const float*)d_in[12];
    const float* bn1_g = (const float*)d_in[13];
    const float* bn1_b = (const float*)d_in[14];
    const float* bn1_m = (const float*)d_in[15];
    const float* bn1_v = (const float*)d_in[16];
    const float* bn2_g = (const float*)d_in[17];
    const float* bn2_b = (const float*)d_in[18];
    const float* bn2_m = (const float*)d_in[19];
    const float* bn2_v = (const float*)d_in[20];
    const float* bn3_g = (const float*)d_in[21];
    const float* bn3_b = (const float*)d_in[22];
    const float* bn3_m = (const float*)d_in[23];
    const float* bn3_v = (const float*)d_in[24];
    const float* fc_w  = (const float*)d_in[25];
    const float* fc_b  = (const float*)d_in[26];
    float* out = (float*)d_out;

    char* wsb = (char*)d_ws;
    float* ws    = (float*)d_ws;
    float* dyn_w = ws;                  // 864 f
    float* bn1_s = ws + 864;
    float* bn1_t = ws + 896;
    float* bn2_s = ws + 928;
    float* bn2_t = ws + 992;
    float* bn3_s = ws + 1056;
    float* bn3_t = ws + 1184;
    float* feat  = ws + 1312;           // 4096 f
    float* h2g   = ws + 5408;           // 256 f
    unsigned short* wrep2 = (unsigned short*)(wsb + 32768);    // 18432 ush
    unsigned short* wrep3 = (unsigned short*)(wsb + 69632);    // 73728 ush
    unsigned short* act1  = (unsigned short*)(wsb + 262144);   // 25.7MB
    unsigned short* act2  = (unsigned short*)(wsb + 262144 + 25690112); // 12.8MB

    gen_small<<<1, 256, 0, stream>>>(
        w1, b1, w2, b2, wb, bb, conv2_b, conv3_b,
        bn1_g, bn1_b, bn1_m, bn1_v, bn2_g, bn2_b, bn2_m, bn2_v,
        bn3_g, bn3_b, bn3_m, bn3_v,
        h2g, bn1_s, bn1_t, bn2_s, bn2_t, bn3_s, bn3_t, feat);

    gen_dynw_repack<<<576, 256, 0, stream>>>(
        w3, b3, h2g, conv2_w, conv3_w, dyn_w, wrep2, wrep3);

    conv1_pool<<<dim3(7, 7, BATCH), 256, 0, stream>>>(
        x, dyn_w, bn1_s, bn1_t, act1);

    conv2_mfma<<<dim3(7, 7, BATCH), 256, 0, stream>>>(
        act1, wrep2, bn2_s, bn2_t, act2);

    conv3_mfma<<<dim3(4, 4, BATCH*2), 256, 0, stream>>>(
        act2, wrep3, bn3_s, bn3_t, feat);

    fc_kernel<<<(BATCH*100 + 255)/256, 256, 0, stream>>>(feat, fc_w, fc_b, out);
}

// Round 4
// 242.307 us; speedup vs baseline: 2.9514x; 2.9514x over previous
//
#include <hip/hip_runtime.h>
#include <hip/hip_bf16.h>

#define BATCH 32
#define HW1 224

typedef __attribute__((ext_vector_type(8))) short short8;
typedef __attribute__((ext_vector_type(4))) float floatx4;

static __device__ __forceinline__ unsigned short f2bf(float f) {
    unsigned int u = __float_as_uint(f);
    unsigned int r = (u + 0x7fffu + ((u >> 16) & 1u)) >> 16;   // RNE
    return (unsigned short)r;
}

// ---------------------------------------------------------------------------
// Kernel A1: tiny MLP front (h1,h2), BN const folding, feat zero. One block.
// ---------------------------------------------------------------------------
__global__ __launch_bounds__(256) void gen_small(
    const float* __restrict__ w1, const float* __restrict__ b1,
    const float* __restrict__ w2, const float* __restrict__ b2,
    const float* __restrict__ wb, const float* __restrict__ bb,
    const float* __restrict__ conv2_b, const float* __restrict__ conv3_b,
    const float* __restrict__ bn1_g, const float* __restrict__ bn1_b,
    const float* __restrict__ bn1_m, const float* __restrict__ bn1_v,
    const float* __restrict__ bn2_g, const float* __restrict__ bn2_b,
    const float* __restrict__ bn2_m, const float* __restrict__ bn2_v,
    const float* __restrict__ bn3_g, const float* __restrict__ bn3_b,
    const float* __restrict__ bn3_m, const float* __restrict__ bn3_v,
    float* __restrict__ h2g,
    float* __restrict__ bn1_s, float* __restrict__ bn1_t,
    float* __restrict__ bn2_s, float* __restrict__ bn2_t,
    float* __restrict__ bn3_s, float* __restrict__ bn3_t,
    float* __restrict__ feat)
{
    __shared__ float h1[128];
    const int t = threadIdx.x;

    if (t < 128) {
        float s = b1[t] + w1[t*3+0] + w1[t*3+1] + w1[t*3+2];
        h1[t] = fmaxf(s, 0.f);
    }
    __syncthreads();
    {
        float s = b2[t];
        const float* wr = w2 + (size_t)t*128;
#pragma unroll 4
        for (int k = 0; k < 128; k += 4) {
            float4 wv = *(const float4*)(wr + k);
            s = fmaf(wv.x, h1[k  ], s);
            s = fmaf(wv.y, h1[k+1], s);
            s = fmaf(wv.z, h1[k+2], s);
            s = fmaf(wv.w, h1[k+3], s);
        }
        h2g[t] = fmaxf(s, 0.f);
    }
    if (t < 32) {
        float dynb = bb[t] + wb[t*3+0] + wb[t*3+1] + wb[t*3+2];
        float s = bn1_g[t] / sqrtf(bn1_v[t] + 1e-5f);
        bn1_s[t] = s;
        bn1_t[t] = (dynb - bn1_m[t]) * s + bn1_b[t];
    }
    if (t < 64) {
        float s = bn2_g[t] / sqrtf(bn2_v[t] + 1e-5f);
        bn2_s[t] = s;
        bn2_t[t] = (conv2_b[t] - bn2_m[t]) * s + bn2_b[t];
    }
    if (t < 128) {
        float s = bn3_g[t] / sqrtf(bn3_v[t] + 1e-5f);
        bn3_s[t] = s;
        bn3_t[t] = (conv3_b[t] - bn3_m[t]) * s + bn3_b[t];
    }
    for (int i = t; i < BATCH*128; i += 256) feat[i] = 0.f;
}

// ---------------------------------------------------------------------------
// Kernel A2: dwt[tap][oc] = (W3 @ h2 + b3) transposed  (wave-per-row dot,
// blocks [0,216)); conv2/conv3 weight repack to [tap][OC][IC] bf16
// (blocks [216,576)).
// ---------------------------------------------------------------------------
__global__ __launch_bounds__(256) void gen_dynw_repack(
    const float* __restrict__ w3, const float* __restrict__ b3,
    const float* __restrict__ h2g,
    const float* __restrict__ conv2_w, const float* __restrict__ conv3_w,
    float* __restrict__ dwt,
    unsigned short* __restrict__ wrep2, unsigned short* __restrict__ wrep3)
{
    __shared__ float h2s[256];
    const int blk = blockIdx.x;
    if (blk < 216) {
        h2s[threadIdx.x] = h2g[threadIdx.x];
        __syncthreads();
        const int wave = threadIdx.x >> 6, lane = threadIdx.x & 63;
        const int row = blk*4 + wave;          // row = oc*27 + tap
        float4 wv = *(const float4*)(w3 + (size_t)row*256 + lane*4);
        float4 hv = *(const float4*)&h2s[lane*4];
        float s = wv.x*hv.x + wv.y*hv.y + wv.z*hv.z + wv.w*hv.w;
#pragma unroll
        for (int m = 1; m < 64; m <<= 1) s += __shfl_xor(s, m);
        if (lane == 0) {
            int oc = row / 27, tap = row - oc*27;
            dwt[tap*32 + oc] = s + b3[row];
        }
    } else {
        const int i = (blk - 216)*256 + threadIdx.x;
        const int N2 = 9*64*32;   // 18432
        if (i < N2) {
            int t = i / (64*32); int rem = i - t*(64*32);
            int oc = rem >> 5, ic = rem & 31;
            wrep2[i] = f2bf(conv2_w[(oc*32 + ic)*9 + t]);
        } else {
            int j = i - N2;       // j < 9*128*64
            int t = j / (128*64); int rem = j - t*(128*64);
            int oc = rem >> 6, ic = rem & 63;
            wrep3[j] = f2bf(conv3_w[(oc*64 + ic)*9 + t]);
        }
    }
}

// ---------------------------------------------------------------------------
// Kernel B: conv1 (3->32, 224x224, pad1) + bn + relu + 2x2 maxpool.
// Weights are block-uniform -> read from dwt[tap][oc] as SCALAR loads (SGPRs).
// Per 4-oc group x channel: reload 4x4 patch from LDS (8 ds_read_b64),
// 144 v_fma with SGPR weight operand. acc[4][4]+p[4][4] = ~50 VGPRs, no spill.
// Output bf16 channel-last act1[b][112][112][32].
// ---------------------------------------------------------------------------
__global__ __launch_bounds__(256) void conv1_pool(
    const float* __restrict__ x, const float* __restrict__ dwt,
    const float* __restrict__ bn_s, const float* __restrict__ bn_t,
    unsigned short* __restrict__ act1)
{
    constexpr int PS = 36;
    __shared__ __align__(16) float sp[3*34*PS];     // 14688 B

    const int tid = threadIdx.x;
    const int bx = blockIdx.x, by = blockIdx.y, b = blockIdx.z;
    const int gx0 = bx*32 - 1, gy0 = by*32 - 1;
    const float* xb = x + (size_t)b * 3 * HW1 * HW1;

    for (int i = tid; i < 3*34*34; i += 256) {
        int ch = i / 1156; int rem = i - ch*1156;
        int r = rem / 34, c = rem - r*34;
        int gy = gy0 + r, gx = gx0 + c;
        float v = 0.f;
        if ((unsigned)gy < HW1 && (unsigned)gx < HW1)
            v = xb[(ch*HW1 + gy)*HW1 + gx];
        sp[(ch*34 + r)*PS + c] = v;
    }
    __syncthreads();

    const int tx = tid & 15, ty = tid >> 4;
    const int py = by*16 + ty, px = bx*16 + tx;
    unsigned short* dst = act1 + ((size_t)((b*112 + py)*112 + px))*32;

#pragma unroll 1
    for (int g = 0; g < 8; ++g) {            // 4 oc per group
        float acc[4][4];
#pragma unroll
        for (int o = 0; o < 4; ++o)
#pragma unroll
            for (int q = 0; q < 4; ++q) acc[o][q] = 0.f;

#pragma unroll
        for (int ch = 0; ch < 3; ++ch) {
            float p[4][4];
#pragma unroll
            for (int r = 0; r < 4; ++r) {
                const float* rp = &sp[(ch*34 + 2*ty + r)*PS + 2*tx];
                float2 a  = *(const float2*)rp;
                float2 bq = *(const float2*)(rp + 2);
                p[r][0] = a.x;  p[r][1] = a.y;
                p[r][2] = bq.x; p[r][3] = bq.y;
            }
#pragma unroll
            for (int ky = 0; ky < 3; ++ky)
#pragma unroll
                for (int kx = 0; kx < 3; ++kx) {
                    const float* wp = &dwt[(ch*9 + ky*3 + kx)*32 + g*4];
#pragma unroll
                    for (int o = 0; o < 4; ++o) {
                        float w = wp[o];      // uniform -> s_load, SGPR operand
                        acc[o][0] = fmaf(w, p[ky  ][kx  ], acc[o][0]);
                        acc[o][1] = fmaf(w, p[ky  ][kx+1], acc[o][1]);
                        acc[o][2] = fmaf(w, p[ky+1][kx  ], acc[o][2]);
                        acc[o][3] = fmaf(w, p[ky+1][kx+1], acc[o][3]);
                    }
                }
        }

        unsigned int pk[2];
#pragma unroll
        for (int o = 0; o < 4; ++o) {
            int oc = g*4 + o;
            float s = bn_s[oc], t = bn_t[oc];   // uniform -> SGPR
            float m = fmaxf(fmaxf(fmaf(acc[o][0], s, t), fmaf(acc[o][1], s, t)),
                            fmaxf(fmaf(acc[o][2], s, t), fmaf(acc[o][3], s, t)));
            m = fmaxf(m, 0.f);
            unsigned short us = f2bf(m);
            if (o & 1) pk[o >> 1] |= ((unsigned int)us) << 16;
            else       pk[o >> 1]  = us;
        }
        *(uint2*)(dst + g*4) = *(uint2*)pk;
    }
}

// ---------------------------------------------------------------------------
// Kernel C: conv2 (32->64, 112x112) bf16 MFMA + bn + relu + 2x2 maxpool.
// ---------------------------------------------------------------------------
__global__ __launch_bounds__(256) void conv2_mfma(
    const unsigned short* __restrict__ act1,
    const unsigned short* __restrict__ wrep,
    const float* __restrict__ bn_s, const float* __restrict__ bn_t,
    unsigned short* __restrict__ act2)
{
    constexpr int IC = 32, OC = 64, H = 112;
    __shared__ __align__(16) short lds[4*18*18*8];   // [chunk][y][x][8ic]

    const int tid = threadIdx.x;
    const int b = blockIdx.z;
    const int cx0 = blockIdx.x*16, cy0 = blockIdx.y*16;
    const unsigned short* ab = act1 + (size_t)b*H*H*IC;

    for (int s = tid; s < 4*324; s += 256) {
        int ck = s / 324; int rem = s - ck*324;
        int y = rem / 18, xx = rem - y*18;
        int gy = cy0 - 1 + y, gx = cx0 - 1 + xx;
        uint4 v = {0,0,0,0};
        if ((unsigned)gy < H && (unsigned)gx < H)
            v = *(const uint4*)(ab + (size_t)(gy*H + gx)*IC + ck*8);
        *(uint4*)&lds[s*8] = v;
    }

    const int lane = tid & 63, wave = tid >> 6;
    const int n = lane & 15, quad = lane >> 4;
    const int oc0w = wave * 16;

    short8 afr[9];
#pragma unroll
    for (int t = 0; t < 9; ++t)
        afr[t] = *(const short8*)(wrep + (size_t)(t*OC + oc0w + n)*IC + quad*8);

    float4 sv = *(const float4*)(bn_s + oc0w + quad*4);
    float4 tv = *(const float4*)(bn_t + oc0w + quad*4);

    __syncthreads();

    for (int ry = 0; ry < 8; ++ry) {
        floatx4 acc0 = {0.f,0.f,0.f,0.f};
        floatx4 acc1 = {0.f,0.f,0.f,0.f};
        int y0 = 2*ry;
#pragma unroll
        for (int ky = 0; ky < 3; ++ky)
#pragma unroll
            for (int kx = 0; kx < 3; ++kx) {
                int t = ky*3 + kx;
                short8 b0 = *(const short8*)&lds[((quad*18 + y0+ky  )*18 + n+kx)*8];
                short8 b1 = *(const short8*)&lds[((quad*18 + y0+1+ky)*18 + n+kx)*8];
                acc0 = __builtin_amdgcn_mfma_f32_16x16x32_bf16(afr[t], b0, acc0, 0, 0, 0);
                acc1 = __builtin_amdgcn_mfma_f32_16x16x32_bf16(afr[t], b1, acc1, 0, 0, 0);
            }
        unsigned int pk[2];
        float sj[4] = {sv.x, sv.y, sv.z, sv.w};
        float tj[4] = {tv.x, tv.y, tv.z, tv.w};
#pragma unroll
        for (int j = 0; j < 4; ++j) {
            float va = fmaxf(fmaf(acc0[j], sj[j], tj[j]), 0.f);
            float vb = fmaxf(fmaf(acc1[j], sj[j], tj[j]), 0.f);
            float m  = fmaxf(va, vb);
            m = fmaxf(m, __shfl_xor(m, 1));
            unsigned short us = f2bf(m);
            if (j & 1) pk[j >> 1] |= ((unsigned int)us) << 16;
            else       pk[j >> 1]  = us;
        }
        if (!(n & 1)) {
            int py = (cy0 >> 1) + ry, px = (cx0 >> 1) + (n >> 1);
            unsigned short* dst = act2 + ((size_t)((b*56 + py)*56 + px))*OC + oc0w + quad*4;
            *(uint2*)dst = *(uint2*)pk;
        }
    }
}

// ---------------------------------------------------------------------------
// Kernel D: conv3 (64->128, 56x56) bf16 MFMA + bn + relu + spatial mean sum.
// ---------------------------------------------------------------------------
__global__ __launch_bounds__(256) void conv3_mfma(
    const unsigned short* __restrict__ act2,
    const unsigned short* __restrict__ wrep,
    const float* __restrict__ bn_s, const float* __restrict__ bn_t,
    float* __restrict__ feat)
{
    constexpr int IC = 64, OC = 128, H = 56;
    __shared__ __align__(16) short lds[8*18*18*8];

    const int tid = threadIdx.x;
    const int b = blockIdx.z >> 1, half = blockIdx.z & 1;
    const int cx0 = blockIdx.x*16, cy0 = blockIdx.y*16;
    const unsigned short* ab = act2 + (size_t)b*H*H*IC;

    for (int s = tid; s < 8*324; s += 256) {
        int ck = s / 324; int rem = s - ck*324;
        int y = rem / 18, xx = rem - y*18;
        int gy = cy0 - 1 + y, gx = cx0 - 1 + xx;
        uint4 v = {0,0,0,0};
        if ((unsigned)gy < H && (unsigned)gx < H)
            v = *(const uint4*)(ab + (size_t)(gy*H + gx)*IC + ck*8);
        *(uint4*)&lds[s*8] = v;
    }

    const int lane = tid & 63, wave = tid >> 6;
    const int n = lane & 15, quad = lane >> 4;
    const int oc0w = half*64 + wave*16;

    short8 afr[18];
#pragma unroll
    for (int t = 0; t < 9; ++t)
#pragma unroll
        for (int kc = 0; kc < 2; ++kc)
            afr[t*2 + kc] = *(const short8*)(wrep + (size_t)(t*OC + oc0w + n)*IC + kc*32 + quad*8);

    float4 sv = *(const float4*)(bn_s + oc0w + quad*4);
    float4 tv = *(const float4*)(bn_t + oc0w + quad*4);

    __syncthreads();

    float sum[4] = {0.f, 0.f, 0.f, 0.f};
    const bool vx = (cx0 + n) < H;
    const int ymax = (H - cy0) < 16 ? (H - cy0) : 16;
    float sj[4] = {sv.x, sv.y, sv.z, sv.w};
    float tj[4] = {tv.x, tv.y, tv.z, tv.w};

    for (int y = 0; y < ymax; ++y) {
        floatx4 acc0 = {0.f,0.f,0.f,0.f};
        floatx4 acc1 = {0.f,0.f,0.f,0.f};
#pragma unroll
        for (int ky = 0; ky < 3; ++ky)
#pragma unroll
            for (int kx = 0; kx < 3; ++kx) {
                int t = ky*3 + kx;
                short8 b0 = *(const short8*)&lds[(((0*4 + quad)*18 + y+ky)*18 + n+kx)*8];
                short8 b1 = *(const short8*)&lds[(((1*4 + quad)*18 + y+ky)*18 + n+kx)*8];
                acc0 = __builtin_amdgcn_mfma_f32_16x16x32_bf16(afr[t*2+0], b0, acc0, 0, 0, 0);
                acc1 = __builtin_amdgcn_mfma_f32_16x16x32_bf16(afr[t*2+1], b1, acc1, 0, 0, 0);
            }
        if (vx) {
#pragma unroll
            for (int j = 0; j < 4; ++j)
                sum[j] += fmaxf(fmaf(acc0[j] + acc1[j], sj[j], tj[j]), 0.f);
        }
    }
#pragma unroll
    for (int j = 0; j < 4; ++j) {
        sum[j] += __shfl_xor(sum[j], 1);
        sum[j] += __shfl_xor(sum[j], 2);
        sum[j] += __shfl_xor(sum[j], 4);
        sum[j] += __shfl_xor(sum[j], 8);
    }
    if (n == 0) {
#pragma unroll
        for (int j = 0; j < 4; ++j)
            atomicAdd(&feat[b*128 + oc0w + quad*4 + j], sum[j]);
    }
}

// ---------------------------------------------------------------------------
// Kernel E: FC head.
// ---------------------------------------------------------------------------
__global__ __launch_bounds__(256) void fc_kernel(
    const float* __restrict__ feat, const float* __restrict__ fc_w,
    const float* __restrict__ fc_b, float* __restrict__ out)
{
    int i = blockIdx.x * 256 + threadIdx.x;
    if (i >= BATCH*100) return;
    int b = i / 100, n = i - b*100;
    const float* f = feat + b*128;
    const float* w = fc_w + n*128;
    float s = 0.f;
#pragma unroll 4
    for (int k = 0; k < 128; ++k) s = fmaf(f[k], w[k], s);
    out[i] = s * (1.f/3136.f) + fc_b[n];
}

extern "C" void kernel_launch(void* const* d_in, const int* in_sizes, int n_in,
                              void* d_out, int out_size, void* d_ws, size_t ws_size,
                              hipStream_t stream)
{
    const float* x       = (const float*)d_in[0];
    const float* w1      = (const float*)d_in[1];
    const float* b1      = (const float*)d_in[2];
    const float* w2      = (const float*)d_in[3];
    const float* b2      = (const float*)d_in[4];
    const float* w3      = (const float*)d_in[5];
    const float* b3      = (const float*)d_in[6];
    const float* wb      = (const float*)d_in[7];
    const float* bb      = (const float*)d_in[8];
    const float* conv2_w = (const float*)d_in[9];
    const float* conv2_b = (const float*)d_in[10];
    const float* conv3_w = (const float*)d_in[11];
    const float* conv3_b = (const float*)d_in[12];
    const float* bn1_g = (const float*)d_in[13];
    const float* bn1_b = (const float*)d_in[14];
    const float* bn1_m = (const float*)d_in[15];
    const float* bn1_v = (const float*)d_in[16];
    const float* bn2_g = (const float*)d_in[17];
    const float* bn2_b = (const float*)d_in[18];
    const float* bn2_m = (const float*)d_in[19];
    const float* bn2_v = (const float*)d_in[20];
    const float* bn3_g = (const float*)d_in[21];
    const float* bn3_b = (const float*)d_in[22];
    const float* bn3_m = (const float*)d_in[23];
    const float* bn3_v = (const float*)d_in[24];
    const float* fc_w  = (const float*)d_in[25];
    const float* fc_b  = (const float*)d_in[26];
    float* out = (float*)d_out;

    char* wsb = (char*)d_ws;
    float* ws    = (float*)d_ws;
    float* dwt   = ws;                  // 864 f (transposed [tap][oc])
    float* bn1_s = ws + 864;
    float* bn1_t = ws + 896;
    float* bn2_s = ws + 928;
    float* bn2_t = ws + 992;
    float* bn3_s = ws + 1056;
    float* bn3_t = ws + 1184;
    float* feat  = ws + 1312;           // 4096 f
    float* h2g   = ws + 5408;           // 256 f
    unsigned short* wrep2 = (unsigned short*)(wsb + 32768);    // 18432 ush
    unsigned short* wrep3 = (unsigned short*)(wsb + 69632);    // 73728 ush
    unsigned short* act1  = (unsigned short*)(wsb + 262144);   // 25.7MB
    unsigned short* act2  = (unsigned short*)(wsb + 262144 + 25690112); // 12.8MB

    gen_small<<<1, 256, 0, stream>>>(
        w1, b1, w2, b2, wb, bb, conv2_b, conv3_b,
        bn1_g, bn1_b, bn1_m, bn1_v, bn2_g, bn2_b, bn2_m, bn2_v,
        bn3_g, bn3_b, bn3_m, bn3_v,
        h2g, bn1_s, bn1_t, bn2_s, bn2_t, bn3_s, bn3_t, feat);

    gen_dynw_repack<<<576, 256, 0, stream>>>(
        w3, b3, h2g, conv2_w, conv3_w, dwt, wrep2, wrep3);

    conv1_pool<<<dim3(7, 7, BATCH), 256, 0, stream>>>(
        x, dwt, bn1_s, bn1_t, act1);

    conv2_mfma<<<dim3(7, 7, BATCH), 256, 0, stream>>>(
        act1, wrep2, bn2_s, bn2_t, act2);

    conv3_mfma<<<dim3(4, 4, BATCH*2), 256, 0, stream>>>(
        act2, wrep3, bn3_s, bn3_t, feat);

    fc_kernel<<<(BATCH*100 + 255)/256, 256, 0, stream>>>(feat, fc_w, fc_b, out);
}

// Round 5
// 241.088 us; speedup vs baseline: 2.9663x; 1.0051x over previous
//
#include <hip/hip_runtime.h>
#include <hip/hip_bf16.h>

#define BATCH 32
#define HW1 224

typedef __attribute__((ext_vector_type(8))) short short8;
typedef __attribute__((ext_vector_type(4))) float floatx4;

static __device__ __forceinline__ unsigned short f2bf(float f) {
    unsigned int u = __float_as_uint(f);
    unsigned int r = (u + 0x7fffu + ((u >> 16) & 1u)) >> 16;   // RNE
    return (unsigned short)r;
}

// ---------------------------------------------------------------------------
// Kernel A1: BN const folding + feat zero. One block, tiny.
// ---------------------------------------------------------------------------
__global__ __launch_bounds__(256) void gen_small(
    const float* __restrict__ wb, const float* __restrict__ bb,
    const float* __restrict__ conv2_b, const float* __restrict__ conv3_b,
    const float* __restrict__ bn1_g, const float* __restrict__ bn1_b,
    const float* __restrict__ bn1_m, const float* __restrict__ bn1_v,
    const float* __restrict__ bn2_g, const float* __restrict__ bn2_b,
    const float* __restrict__ bn2_m, const float* __restrict__ bn2_v,
    const float* __restrict__ bn3_g, const float* __restrict__ bn3_b,
    const float* __restrict__ bn3_m, const float* __restrict__ bn3_v,
    float* __restrict__ bn1_s, float* __restrict__ bn1_t,
    float* __restrict__ bn2_s, float* __restrict__ bn2_t,
    float* __restrict__ bn3_s, float* __restrict__ bn3_t,
    float* __restrict__ feat)
{
    const int t = threadIdx.x;
    if (t < 32) {
        float dynb = bb[t] + wb[t*3+0] + wb[t*3+1] + wb[t*3+2];
        float s = bn1_g[t] / sqrtf(bn1_v[t] + 1e-5f);
        bn1_s[t] = s;
        bn1_t[t] = (dynb - bn1_m[t]) * s + bn1_b[t];
    }
    if (t < 64) {
        float s = bn2_g[t] / sqrtf(bn2_v[t] + 1e-5f);
        bn2_s[t] = s;
        bn2_t[t] = (conv2_b[t] - bn2_m[t]) * s + bn2_b[t];
    }
    if (t < 128) {
        float s = bn3_g[t] / sqrtf(bn3_v[t] + 1e-5f);
        bn3_s[t] = s;
        bn3_t[t] = (conv3_b[t] - bn3_m[t]) * s + bn3_b[t];
    }
    for (int i = t; i < BATCH*128; i += 256) feat[i] = 0.f;
}

// ---------------------------------------------------------------------------
// Kernel A2: blocks [0,216): recompute h1/h2 locally (w2 from L2), then
// dwt[tap][oc] = (W3 @ h2 + b3) transposed, wave-per-row dot.
// Blocks [216,576): conv2/conv3 weight repack to [tap][OC][IC] bf16.
// ---------------------------------------------------------------------------
__global__ __launch_bounds__(256) void gen_dynw_repack(
    const float* __restrict__ w1, const float* __restrict__ b1,
    const float* __restrict__ w2, const float* __restrict__ b2,
    const float* __restrict__ w3, const float* __restrict__ b3,
    const float* __restrict__ conv2_w, const float* __restrict__ conv3_w,
    float* __restrict__ dwt,
    unsigned short* __restrict__ wrep2, unsigned short* __restrict__ wrep3)
{
    __shared__ float h1s[128];
    __shared__ float h2s[256];
    const int blk = blockIdx.x;
    const int t = threadIdx.x;
    if (blk < 216) {
        if (t < 128) {
            float s = b1[t] + w1[t*3+0] + w1[t*3+1] + w1[t*3+2];
            h1s[t] = fmaxf(s, 0.f);
        }
        __syncthreads();
        {
            float s = b2[t];
            const float* wr = w2 + (size_t)t*128;
#pragma unroll 4
            for (int k = 0; k < 128; k += 4) {
                float4 wv = *(const float4*)(wr + k);
                s = fmaf(wv.x, h1s[k  ], s);
                s = fmaf(wv.y, h1s[k+1], s);
                s = fmaf(wv.z, h1s[k+2], s);
                s = fmaf(wv.w, h1s[k+3], s);
            }
            h2s[t] = fmaxf(s, 0.f);
        }
        __syncthreads();
        const int wave = t >> 6, lane = t & 63;
        const int row = blk*4 + wave;          // row = oc*27 + tap
        float4 wv = *(const float4*)(w3 + (size_t)row*256 + lane*4);
        float4 hv = *(const float4*)&h2s[lane*4];
        float s = wv.x*hv.x + wv.y*hv.y + wv.z*hv.z + wv.w*hv.w;
#pragma unroll
        for (int m = 1; m < 64; m <<= 1) s += __shfl_xor(s, m);
        if (lane == 0) {
            int oc = row / 27, tap = row - oc*27;
            dwt[tap*32 + oc] = s + b3[row];
        }
    } else {
        const int i = (blk - 216)*256 + t;
        const int N2 = 9*64*32;   // 18432
        if (i < N2) {
            int tp = i / (64*32); int rem = i - tp*(64*32);
            int oc = rem >> 5, ic = rem & 31;
            wrep2[i] = f2bf(conv2_w[(oc*32 + ic)*9 + tp]);
        } else {
            int j = i - N2;       // j < 9*128*64
            int tp = j / (128*64); int rem = j - tp*(128*64);
            int oc = rem >> 6, ic = rem & 63;
            wrep3[j] = f2bf(conv3_w[(oc*64 + ic)*9 + tp]);
        }
    }
}

// ---------------------------------------------------------------------------
// Kernel B: conv1 (3->32, 224x224, pad1) + bn + relu + 2x2 maxpool.
// Patch p[3][4][4] RESIDENT in registers (loaded once, 24 ds_read_b64);
// 8 groups x 4 oc with SGPR weights from dwt[tap][oc]. ~80 VGPR, no bounds
// cap (R3 lesson: never pair min-waves with a big explicit working set).
// Output bf16 channel-last act1[b][112][112][32].
// ---------------------------------------------------------------------------
__global__ __launch_bounds__(256) void conv1_pool(
    const float* __restrict__ x, const float* __restrict__ dwt,
    const float* __restrict__ bn_s, const float* __restrict__ bn_t,
    unsigned short* __restrict__ act1)
{
    constexpr int PS = 36;
    __shared__ __align__(16) float sp[3*34*PS];     // 14688 B

    const int tid = threadIdx.x;
    const int bx = blockIdx.x, by = blockIdx.y, b = blockIdx.z;
    const int gx0 = bx*32 - 1, gy0 = by*32 - 1;
    const float* xb = x + (size_t)b * 3 * HW1 * HW1;

    for (int i = tid; i < 3*34*34; i += 256) {
        int ch = i / 1156; int rem = i - ch*1156;
        int r = rem / 34, c = rem - r*34;
        int gy = gy0 + r, gx = gx0 + c;
        float v = 0.f;
        if ((unsigned)gy < HW1 && (unsigned)gx < HW1)
            v = xb[(ch*HW1 + gy)*HW1 + gx];
        sp[(ch*34 + r)*PS + c] = v;
    }
    __syncthreads();

    const int tx = tid & 15, ty = tid >> 4;

    float p[3][4][4];                   // resident patch, 48 VGPRs
#pragma unroll
    for (int ch = 0; ch < 3; ++ch)
#pragma unroll
        for (int r = 0; r < 4; ++r) {
            const float* rp = &sp[(ch*34 + 2*ty + r)*PS + 2*tx];
            float2 a  = *(const float2*)rp;
            float2 bq = *(const float2*)(rp + 2);
            p[ch][r][0] = a.x;  p[ch][r][1] = a.y;
            p[ch][r][2] = bq.x; p[ch][r][3] = bq.y;
        }

    const int py = by*16 + ty, px = bx*16 + tx;
    unsigned short* dst = act1 + ((size_t)((b*112 + py)*112 + px))*32;

#pragma unroll 1
    for (int g = 0; g < 8; ++g) {            // 4 oc per group
        float acc[4][4];
#pragma unroll
        for (int o = 0; o < 4; ++o)
#pragma unroll
            for (int q = 0; q < 4; ++q) acc[o][q] = 0.f;

#pragma unroll
        for (int ch = 0; ch < 3; ++ch)
#pragma unroll
            for (int ky = 0; ky < 3; ++ky)
#pragma unroll
                for (int kx = 0; kx < 3; ++kx) {
                    const float* wp = &dwt[(ch*9 + ky*3 + kx)*32 + g*4];
#pragma unroll
                    for (int o = 0; o < 4; ++o) {
                        float w = wp[o];      // uniform -> SGPR operand
                        acc[o][0] = fmaf(w, p[ch][ky  ][kx  ], acc[o][0]);
                        acc[o][1] = fmaf(w, p[ch][ky  ][kx+1], acc[o][1]);
                        acc[o][2] = fmaf(w, p[ch][ky+1][kx  ], acc[o][2]);
                        acc[o][3] = fmaf(w, p[ch][ky+1][kx+1], acc[o][3]);
                    }
                }

        unsigned int pk[2];
#pragma unroll
        for (int o = 0; o < 4; ++o) {
            int oc = g*4 + o;
            float s = bn_s[oc], t = bn_t[oc];
            float m = fmaxf(fmaxf(fmaf(acc[o][0], s, t), fmaf(acc[o][1], s, t)),
                            fmaxf(fmaf(acc[o][2], s, t), fmaf(acc[o][3], s, t)));
            m = fmaxf(m, 0.f);
            unsigned short us = f2bf(m);
            if (o & 1) pk[o >> 1] |= ((unsigned int)us) << 16;
            else       pk[o >> 1]  = us;
        }
        *(uint2*)(dst + g*4) = *(uint2*)pk;
    }
}

// ---------------------------------------------------------------------------
// Kernel C: conv2 (32->64, 112x112) bf16 MFMA + bn + relu + 2x2 maxpool.
// ---------------------------------------------------------------------------
__global__ __launch_bounds__(256) void conv2_mfma(
    const unsigned short* __restrict__ act1,
    const unsigned short* __restrict__ wrep,
    const float* __restrict__ bn_s, const float* __restrict__ bn_t,
    unsigned short* __restrict__ act2)
{
    constexpr int IC = 32, OC = 64, H = 112;
    __shared__ __align__(16) short lds[4*18*18*8];   // [chunk][y][x][8ic]

    const int tid = threadIdx.x;
    const int b = blockIdx.z;
    const int cx0 = blockIdx.x*16, cy0 = blockIdx.y*16;
    const unsigned short* ab = act1 + (size_t)b*H*H*IC;

    for (int s = tid; s < 4*324; s += 256) {
        int ck = s / 324; int rem = s - ck*324;
        int y = rem / 18, xx = rem - y*18;
        int gy = cy0 - 1 + y, gx = cx0 - 1 + xx;
        uint4 v = {0,0,0,0};
        if ((unsigned)gy < H && (unsigned)gx < H)
            v = *(const uint4*)(ab + (size_t)(gy*H + gx)*IC + ck*8);
        *(uint4*)&lds[s*8] = v;
    }

    const int lane = tid & 63, wave = tid >> 6;
    const int n = lane & 15, quad = lane >> 4;
    const int oc0w = wave * 16;

    short8 afr[9];
#pragma unroll
    for (int t = 0; t < 9; ++t)
        afr[t] = *(const short8*)(wrep + (size_t)(t*OC + oc0w + n)*IC + quad*8);

    float4 sv = *(const float4*)(bn_s + oc0w + quad*4);
    float4 tv = *(const float4*)(bn_t + oc0w + quad*4);

    __syncthreads();

    for (int ry = 0; ry < 8; ++ry) {
        floatx4 acc0 = {0.f,0.f,0.f,0.f};
        floatx4 acc1 = {0.f,0.f,0.f,0.f};
        int y0 = 2*ry;
#pragma unroll
        for (int ky = 0; ky < 3; ++ky)
#pragma unroll
            for (int kx = 0; kx < 3; ++kx) {
                int t = ky*3 + kx;
                short8 b0 = *(const short8*)&lds[((quad*18 + y0+ky  )*18 + n+kx)*8];
                short8 b1 = *(const short8*)&lds[((quad*18 + y0+1+ky)*18 + n+kx)*8];
                acc0 = __builtin_amdgcn_mfma_f32_16x16x32_bf16(afr[t], b0, acc0, 0, 0, 0);
                acc1 = __builtin_amdgcn_mfma_f32_16x16x32_bf16(afr[t], b1, acc1, 0, 0, 0);
            }
        unsigned int pk[2];
        float sj[4] = {sv.x, sv.y, sv.z, sv.w};
        float tj[4] = {tv.x, tv.y, tv.z, tv.w};
#pragma unroll
        for (int j = 0; j < 4; ++j) {
            float va = fmaxf(fmaf(acc0[j], sj[j], tj[j]), 0.f);
            float vb = fmaxf(fmaf(acc1[j], sj[j], tj[j]), 0.f);
            float m  = fmaxf(va, vb);
            m = fmaxf(m, __shfl_xor(m, 1));
            unsigned short us = f2bf(m);
            if (j & 1) pk[j >> 1] |= ((unsigned int)us) << 16;
            else       pk[j >> 1]  = us;
        }
        if (!(n & 1)) {
            int py = (cy0 >> 1) + ry, px = (cx0 >> 1) + (n >> 1);
            unsigned short* dst = act2 + ((size_t)((b*56 + py)*56 + px))*OC + oc0w + quad*4;
            *(uint2*)dst = *(uint2*)pk;
        }
    }
}

// ---------------------------------------------------------------------------
// Kernel D: conv3 (64->128, 56x56) bf16 MFMA + bn + relu + spatial mean sum.
// ---------------------------------------------------------------------------
__global__ __launch_bounds__(256) void conv3_mfma(
    const unsigned short* __restrict__ act2,
    const unsigned short* __restrict__ wrep,
    const float* __restrict__ bn_s, const float* __restrict__ bn_t,
    float* __restrict__ feat)
{
    constexpr int IC = 64, OC = 128, H = 56;
    __shared__ __align__(16) short lds[8*18*18*8];

    const int tid = threadIdx.x;
    const int b = blockIdx.z >> 1, half = blockIdx.z & 1;
    const int cx0 = blockIdx.x*16, cy0 = blockIdx.y*16;
    const unsigned short* ab = act2 + (size_t)b*H*H*IC;

    for (int s = tid; s < 8*324; s += 256) {
        int ck = s / 324; int rem = s - ck*324;
        int y = rem / 18, xx = rem - y*18;
        int gy = cy0 - 1 + y, gx = cx0 - 1 + xx;
        uint4 v = {0,0,0,0};
        if ((unsigned)gy < H && (unsigned)gx < H)
            v = *(const uint4*)(ab + (size_t)(gy*H + gx)*IC + ck*8);
        *(uint4*)&lds[s*8] = v;
    }

    const int lane = tid & 63, wave = tid >> 6;
    const int n = lane & 15, quad = lane >> 4;
    const int oc0w = half*64 + wave*16;

    short8 afr[18];
#pragma unroll
    for (int t = 0; t < 9; ++t)
#pragma unroll
        for (int kc = 0; kc < 2; ++kc)
            afr[t*2 + kc] = *(const short8*)(wrep + (size_t)(t*OC + oc0w + n)*IC + kc*32 + quad*8);

    float4 sv = *(const float4*)(bn_s + oc0w + quad*4);
    float4 tv = *(const float4*)(bn_t + oc0w + quad*4);

    __syncthreads();

    float sum[4] = {0.f, 0.f, 0.f, 0.f};
    const bool vx = (cx0 + n) < H;
    const int ymax = (H - cy0) < 16 ? (H - cy0) : 16;
    float sj[4] = {sv.x, sv.y, sv.z, sv.w};
    float tj[4] = {tv.x, tv.y, tv.z, tv.w};

    for (int y = 0; y < ymax; ++y) {
        floatx4 acc0 = {0.f,0.f,0.f,0.f};
        floatx4 acc1 = {0.f,0.f,0.f,0.f};
#pragma unroll
        for (int ky = 0; ky < 3; ++ky)
#pragma unroll
            for (int kx = 0; kx < 3; ++kx) {
                int t = ky*3 + kx;
                short8 b0 = *(const short8*)&lds[(((0*4 + quad)*18 + y+ky)*18 + n+kx)*8];
                short8 b1 = *(const short8*)&lds[(((1*4 + quad)*18 + y+ky)*18 + n+kx)*8];
                acc0 = __builtin_amdgcn_mfma_f32_16x16x32_bf16(afr[t*2+0], b0, acc0, 0, 0, 0);
                acc1 = __builtin_amdgcn_mfma_f32_16x16x32_bf16(afr[t*2+1], b1, acc1, 0, 0, 0);
            }
        if (vx) {
#pragma unroll
            for (int j = 0; j < 4; ++j)
                sum[j] += fmaxf(fmaf(acc0[j] + acc1[j], sj[j], tj[j]), 0.f);
        }
    }
#pragma unroll
    for (int j = 0; j < 4; ++j) {
        sum[j] += __shfl_xor(sum[j], 1);
        sum[j] += __shfl_xor(sum[j], 2);
        sum[j] += __shfl_xor(sum[j], 4);
        sum[j] += __shfl_xor(sum[j], 8);
    }
    if (n == 0) {
#pragma unroll
        for (int j = 0; j < 4; ++j)
            atomicAdd(&feat[b*128 + oc0w + quad*4 + j], sum[j]);
    }
}

// ---------------------------------------------------------------------------
// Kernel E: FC head.
// ---------------------------------------------------------------------------
__global__ __launch_bounds__(256) void fc_kernel(
    const float* __restrict__ feat, const float* __restrict__ fc_w,
    const float* __restrict__ fc_b, float* __restrict__ out)
{
    int i = blockIdx.x * 256 + threadIdx.x;
    if (i >= BATCH*100) return;
    int b = i / 100, n = i - b*100;
    const float* f = feat + b*128;
    const float* w = fc_w + n*128;
    float s = 0.f;
#pragma unroll 4
    for (int k = 0; k < 128; ++k) s = fmaf(f[k], w[k], s);
    out[i] = s * (1.f/3136.f) + fc_b[n];
}

extern "C" void kernel_launch(void* const* d_in, const int* in_sizes, int n_in,
                              void* d_out, int out_size, void* d_ws, size_t ws_size,
                              hipStream_t stream)
{
    const float* x       = (const float*)d_in[0];
    const float* w1      = (const float*)d_in[1];
    const float* b1      = (const float*)d_in[2];
    const float* w2      = (const float*)d_in[3];
    const float* b2      = (const float*)d_in[4];
    const float* w3      = (const float*)d_in[5];
    const float* b3      = (const float*)d_in[6];
    const float* wb      = (const float*)d_in[7];
    const float* bb      = (const float*)d_in[8];
    const float* conv2_w = (const float*)d_in[9];
    const float* conv2_b = (const float*)d_in[10];
    const float* conv3_w = (const float*)d_in[11];
    const float* conv3_b = (const float*)d_in[12];
    const float* bn1_g = (const float*)d_in[13];
    const float* bn1_b = (const float*)d_in[14];
    const float* bn1_m = (const float*)d_in[15];
    const float* bn1_v = (const float*)d_in[16];
    const float* bn2_g = (const float*)d_in[17];
    const float* bn2_b = (const float*)d_in[18];
    const float* bn2_m = (const float*)d_in[19];
    const float* bn2_v = (const float*)d_in[20];
    const float* bn3_g = (const float*)d_in[21];
    const float* bn3_b = (const float*)d_in[22];
    const float* bn3_m = (const float*)d_in[23];
    const float* bn3_v = (const float*)d_in[24];
    const float* fc_w  = (const float*)d_in[25];
    const float* fc_b  = (const float*)d_in[26];
    float* out = (float*)d_out;

    char* wsb = (char*)d_ws;
    float* ws    = (float*)d_ws;
    float* dwt   = ws;                  // 864 f (transposed [tap][oc])
    float* bn1_s = ws + 864;
    float* bn1_t = ws + 896;
    float* bn2_s = ws + 928;
    float* bn2_t = ws + 992;
    float* bn3_s = ws + 1056;
    float* bn3_t = ws + 1184;
    float* feat  = ws + 1312;           // 4096 f
    unsigned short* wrep2 = (unsigned short*)(wsb + 32768);    // 18432 ush
    unsigned short* wrep3 = (unsigned short*)(wsb + 69632);    // 73728 ush
    unsigned short* act1  = (unsigned short*)(wsb + 262144);   // 25.7MB
    unsigned short* act2  = (unsigned short*)(wsb + 262144 + 25690112); // 12.8MB

    gen_small<<<1, 256, 0, stream>>>(
        wb, bb, conv2_b, conv3_b,
        bn1_g, bn1_b, bn1_m, bn1_v, bn2_g, bn2_b, bn2_m, bn2_v,
        bn3_g, bn3_b, bn3_m, bn3_v,
        bn1_s, bn1_t, bn2_s, bn2_t, bn3_s, bn3_t, feat);

    gen_dynw_repack<<<576, 256, 0, stream>>>(
        w1, b1, w2, b2, w3, b3, conv2_w, conv3_w, dwt, wrep2, wrep3);

    conv1_pool<<<dim3(7, 7, BATCH), 256, 0, stream>>>(
        x, dwt, bn1_s, bn1_t, act1);

    conv2_mfma<<<dim3(7, 7, BATCH), 256, 0, stream>>>(
        act1, wrep2, bn2_s, bn2_t, act2);

    conv3_mfma<<<dim3(4, 4, BATCH*2), 256, 0, stream>>>(
        act2, wrep3, bn3_s, bn3_t, feat);

    fc_kernel<<<(BATCH*100 + 255)/256, 256, 0, stream>>>(feat, fc_w, fc_b, out);
}

// Round 6
// 237.644 us; speedup vs baseline: 3.0093x; 1.0145x over previous
//
#include <hip/hip_runtime.h>
#include <hip/hip_bf16.h>

#define BATCH 32
#define HW1 224

typedef __attribute__((ext_vector_type(8))) short short8;
typedef __attribute__((ext_vector_type(4))) float floatx4;

static __device__ __forceinline__ unsigned short f2bf(float f) {
    unsigned int u = __float_as_uint(f);
    unsigned int r = (u + 0x7fffu + ((u >> 16) & 1u)) >> 16;   // RNE
    return (unsigned short)r;
}

// ---------------------------------------------------------------------------
// Kernel A1: BN const folding + feat zero. One block, tiny.
// ---------------------------------------------------------------------------
__global__ __launch_bounds__(256) void gen_small(
    const float* __restrict__ wb, const float* __restrict__ bb,
    const float* __restrict__ conv2_b, const float* __restrict__ conv3_b,
    const float* __restrict__ bn1_g, const float* __restrict__ bn1_b,
    const float* __restrict__ bn1_m, const float* __restrict__ bn1_v,
    const float* __restrict__ bn2_g, const float* __restrict__ bn2_b,
    const float* __restrict__ bn2_m, const float* __restrict__ bn2_v,
    const float* __restrict__ bn3_g, const float* __restrict__ bn3_b,
    const float* __restrict__ bn3_m, const float* __restrict__ bn3_v,
    float* __restrict__ bn1_s, float* __restrict__ bn1_t,
    float* __restrict__ bn2_s, float* __restrict__ bn2_t,
    float* __restrict__ bn3_s, float* __restrict__ bn3_t,
    float* __restrict__ feat)
{
    const int t = threadIdx.x;
    if (t < 32) {
        float dynb = bb[t] + wb[t*3+0] + wb[t*3+1] + wb[t*3+2];
        float s = bn1_g[t] / sqrtf(bn1_v[t] + 1e-5f);
        bn1_s[t] = s;
        bn1_t[t] = (dynb - bn1_m[t]) * s + bn1_b[t];
    }
    if (t < 64) {
        float s = bn2_g[t] / sqrtf(bn2_v[t] + 1e-5f);
        bn2_s[t] = s;
        bn2_t[t] = (conv2_b[t] - bn2_m[t]) * s + bn2_b[t];
    }
    if (t < 128) {
        float s = bn3_g[t] / sqrtf(bn3_v[t] + 1e-5f);
        bn3_s[t] = s;
        bn3_t[t] = (conv3_b[t] - bn3_m[t]) * s + bn3_b[t];
    }
    for (int i = t; i < BATCH*128; i += 256) feat[i] = 0.f;
}

// ---------------------------------------------------------------------------
// Kernel A2: blocks [0,216): recompute h1/h2 locally (w2 from L2), then
// dwt[tap][oc] = (W3 @ h2 + b3) transposed, wave-per-row dot.
// Blocks [216,576): conv2/conv3 weight repack to [tap][OC][IC] bf16.
// ---------------------------------------------------------------------------
__global__ __launch_bounds__(256) void gen_dynw_repack(
    const float* __restrict__ w1, const float* __restrict__ b1,
    const float* __restrict__ w2, const float* __restrict__ b2,
    const float* __restrict__ w3, const float* __restrict__ b3,
    const float* __restrict__ conv2_w, const float* __restrict__ conv3_w,
    float* __restrict__ dwt,
    unsigned short* __restrict__ wrep2, unsigned short* __restrict__ wrep3)
{
    __shared__ float h1s[128];
    __shared__ float h2s[256];
    const int blk = blockIdx.x;
    const int t = threadIdx.x;
    if (blk < 216) {
        if (t < 128) {
            float s = b1[t] + w1[t*3+0] + w1[t*3+1] + w1[t*3+2];
            h1s[t] = fmaxf(s, 0.f);
        }
        __syncthreads();
        {
            float s = b2[t];
            const float* wr = w2 + (size_t)t*128;
#pragma unroll 4
            for (int k = 0; k < 128; k += 4) {
                float4 wv = *(const float4*)(wr + k);
                s = fmaf(wv.x, h1s[k  ], s);
                s = fmaf(wv.y, h1s[k+1], s);
                s = fmaf(wv.z, h1s[k+2], s);
                s = fmaf(wv.w, h1s[k+3], s);
            }
            h2s[t] = fmaxf(s, 0.f);
        }
        __syncthreads();
        const int wave = t >> 6, lane = t & 63;
        const int row = blk*4 + wave;          // row = oc*27 + tap
        float4 wv = *(const float4*)(w3 + (size_t)row*256 + lane*4);
        float4 hv = *(const float4*)&h2s[lane*4];
        float s = wv.x*hv.x + wv.y*hv.y + wv.z*hv.z + wv.w*hv.w;
#pragma unroll
        for (int m = 1; m < 64; m <<= 1) s += __shfl_xor(s, m);
        if (lane == 0) {
            int oc = row / 27, tap = row - oc*27;
            dwt[tap*32 + oc] = s + b3[row];
        }
    } else {
        const int i = (blk - 216)*256 + t;
        const int N2 = 9*64*32;   // 18432
        if (i < N2) {
            int tp = i / (64*32); int rem = i - tp*(64*32);
            int oc = rem >> 5, ic = rem & 31;
            wrep2[i] = f2bf(conv2_w[(oc*32 + ic)*9 + tp]);
        } else {
            int j = i - N2;       // j < 9*128*64
            int tp = j / (128*64); int rem = j - tp*(128*64);
            int oc = rem >> 6, ic = rem & 63;
            wrep3[j] = f2bf(conv3_w[(oc*64 + ic)*9 + tp]);
        }
    }
}

// ---------------------------------------------------------------------------
// Kernel B: conv1 (3->32, 224x224, pad1) + bn + relu + 2x2 maxpool.
// Patch p[3][4][4] pinned in VGPRs via empty asm (defeats LDS-rematerialization
// — R5 lesson: without this the allocator re-reads LDS per oc-group).
// 8 groups x 4 oc with SGPR weights from dwt[tap][oc].
// Output bf16 channel-last act1[b][112][112][32].
// ---------------------------------------------------------------------------
__global__ __launch_bounds__(256) void conv1_pool(
    const float* __restrict__ x, const float* __restrict__ dwt,
    const float* __restrict__ bn_s, const float* __restrict__ bn_t,
    unsigned short* __restrict__ act1)
{
    constexpr int PS = 36;
    __shared__ __align__(16) float sp[3*34*PS];     // 14688 B

    const int tid = threadIdx.x;
    const int bx = blockIdx.x, by = blockIdx.y, b = blockIdx.z;
    const int gx0 = bx*32 - 1, gy0 = by*32 - 1;
    const float* xb = x + (size_t)b * 3 * HW1 * HW1;

    for (int i = tid; i < 3*34*34; i += 256) {
        int ch = i / 1156; int rem = i - ch*1156;
        int r = rem / 34, c = rem - r*34;
        int gy = gy0 + r, gx = gx0 + c;
        float v = 0.f;
        if ((unsigned)gy < HW1 && (unsigned)gx < HW1)
            v = xb[(ch*HW1 + gy)*HW1 + gx];
        sp[(ch*34 + r)*PS + c] = v;
    }
    __syncthreads();

    const int tx = tid & 15, ty = tid >> 4;

    float p[3][4][4];                   // resident patch, 48 VGPRs
#pragma unroll
    for (int ch = 0; ch < 3; ++ch)
#pragma unroll
        for (int r = 0; r < 4; ++r) {
            const float* rp = &sp[(ch*34 + 2*ty + r)*PS + 2*tx];
            float2 a  = *(const float2*)rp;
            float2 bq = *(const float2*)(rp + 2);
            p[ch][r][0] = a.x;  p[ch][r][1] = a.y;
            p[ch][r][2] = bq.x; p[ch][r][3] = bq.y;
        }
    // Pin: make each value's provenance opaque so the register allocator
    // cannot legally rematerialize it from LDS inside the g-loop.
#pragma unroll
    for (int ch = 0; ch < 3; ++ch)
#pragma unroll
        for (int r = 0; r < 4; ++r)
#pragma unroll
            for (int c = 0; c < 4; ++c)
                asm volatile("" : "+v"(p[ch][r][c]));

    const int py = by*16 + ty, px = bx*16 + tx;
    unsigned short* dst = act1 + ((size_t)((b*112 + py)*112 + px))*32;

#pragma unroll 1
    for (int g = 0; g < 8; ++g) {            // 4 oc per group
        float acc[4][4];
#pragma unroll
        for (int o = 0; o < 4; ++o)
#pragma unroll
            for (int q = 0; q < 4; ++q) acc[o][q] = 0.f;

#pragma unroll
        for (int ch = 0; ch < 3; ++ch)
#pragma unroll
            for (int ky = 0; ky < 3; ++ky)
#pragma unroll
                for (int kx = 0; kx < 3; ++kx) {
                    const float* wp = &dwt[(ch*9 + ky*3 + kx)*32 + g*4];
#pragma unroll
                    for (int o = 0; o < 4; ++o) {
                        float w = wp[o];      // uniform -> SGPR operand
                        acc[o][0] = fmaf(w, p[ch][ky  ][kx  ], acc[o][0]);
                        acc[o][1] = fmaf(w, p[ch][ky  ][kx+1], acc[o][1]);
                        acc[o][2] = fmaf(w, p[ch][ky+1][kx  ], acc[o][2]);
                        acc[o][3] = fmaf(w, p[ch][ky+1][kx+1], acc[o][3]);
                    }
                }

        unsigned int pk[2];
#pragma unroll
        for (int o = 0; o < 4; ++o) {
            int oc = g*4 + o;
            float s = bn_s[oc], t = bn_t[oc];
            float m = fmaxf(fmaxf(fmaf(acc[o][0], s, t), fmaf(acc[o][1], s, t)),
                            fmaxf(fmaf(acc[o][2], s, t), fmaf(acc[o][3], s, t)));
            m = fmaxf(m, 0.f);
            unsigned short us = f2bf(m);
            if (o & 1) pk[o >> 1] |= ((unsigned int)us) << 16;
            else       pk[o >> 1]  = us;
        }
        *(uint2*)(dst + g*4) = *(uint2*)pk;
    }
}

// ---------------------------------------------------------------------------
// Kernel C: conv2 (32->64, 112x112) bf16 MFMA + bn + relu + 2x2 maxpool.
// Rolling-row-window: stream the 18 LDS rows once (3 ds_read_b128 each),
// rotate 3 accumulators; each output row receives ky=0/1/2 as rows pass.
// LDS reads/wave: 54 (was 144). MFMA count unchanged (144).
// ---------------------------------------------------------------------------
__global__ __launch_bounds__(256) void conv2_mfma(
    const unsigned short* __restrict__ act1,
    const unsigned short* __restrict__ wrep,
    const float* __restrict__ bn_s, const float* __restrict__ bn_t,
    unsigned short* __restrict__ act2)
{
    constexpr int IC = 32, OC = 64, H = 112;
    __shared__ __align__(16) short lds[4*18*18*8];   // [chunk][y][x][8ic]

    const int tid = threadIdx.x;
    const int b = blockIdx.z;
    const int cx0 = blockIdx.x*16, cy0 = blockIdx.y*16;
    const unsigned short* ab = act1 + (size_t)b*H*H*IC;

    for (int s = tid; s < 4*324; s += 256) {
        int ck = s / 324; int rem = s - ck*324;
        int y = rem / 18, xx = rem - y*18;
        int gy = cy0 - 1 + y, gx = cx0 - 1 + xx;
        uint4 v = {0,0,0,0};
        if ((unsigned)gy < H && (unsigned)gx < H)
            v = *(const uint4*)(ab + (size_t)(gy*H + gx)*IC + ck*8);
        *(uint4*)&lds[s*8] = v;
    }

    const int lane = tid & 63, wave = tid >> 6;
    const int n = lane & 15, quad = lane >> 4;
    const int oc0w = wave * 16;

    short8 afr[9];
#pragma unroll
    for (int t = 0; t < 9; ++t)
        afr[t] = *(const short8*)(wrep + (size_t)(t*OC + oc0w + n)*IC + quad*8);

    float4 sv = *(const float4*)(bn_s + oc0w + quad*4);
    float4 tv = *(const float4*)(bn_t + oc0w + quad*4);
    float sj[4] = {sv.x, sv.y, sv.z, sv.w};
    float tj[4] = {tv.x, tv.y, tv.z, tv.w};

    __syncthreads();

    floatx4 acc[3];
    float ev[4];      // saved even-row post-relu values awaiting odd partner

#pragma unroll
    for (int r = 0; r < 18; ++r) {
        const short* rp = &lds[((quad*18 + r)*18 + n)*8];
        short8 w0 = *(const short8*)(rp);
        short8 w1 = *(const short8*)(rp + 8);
        short8 w2 = *(const short8*)(rp + 16);

        if (r < 16) {                    // ky=0 for y=r (init)
            floatx4 a = {0.f,0.f,0.f,0.f};
            a = __builtin_amdgcn_mfma_f32_16x16x32_bf16(afr[0], w0, a, 0, 0, 0);
            a = __builtin_amdgcn_mfma_f32_16x16x32_bf16(afr[1], w1, a, 0, 0, 0);
            a = __builtin_amdgcn_mfma_f32_16x16x32_bf16(afr[2], w2, a, 0, 0, 0);
            acc[r % 3] = a;
        }
        if (r >= 1 && r <= 16) {         // ky=1 for y=r-1
            int y = r - 1;
            floatx4 a = acc[y % 3];
            a = __builtin_amdgcn_mfma_f32_16x16x32_bf16(afr[3], w0, a, 0, 0, 0);
            a = __builtin_amdgcn_mfma_f32_16x16x32_bf16(afr[4], w1, a, 0, 0, 0);
            a = __builtin_amdgcn_mfma_f32_16x16x32_bf16(afr[5], w2, a, 0, 0, 0);
            acc[y % 3] = a;
        }
        if (r >= 2) {                    // ky=2 for y=r-2, then finalize
            int y = r - 2;
            floatx4 a = acc[y % 3];
            a = __builtin_amdgcn_mfma_f32_16x16x32_bf16(afr[6], w0, a, 0, 0, 0);
            a = __builtin_amdgcn_mfma_f32_16x16x32_bf16(afr[7], w1, a, 0, 0, 0);
            a = __builtin_amdgcn_mfma_f32_16x16x32_bf16(afr[8], w2, a, 0, 0, 0);

            float v[4];
#pragma unroll
            for (int j = 0; j < 4; ++j)
                v[j] = fmaxf(fmaf(a[j], sj[j], tj[j]), 0.f);

            if ((y & 1) == 0) {
#pragma unroll
                for (int j = 0; j < 4; ++j) ev[j] = v[j];
            } else {
                unsigned int pk[2];
#pragma unroll
                for (int j = 0; j < 4; ++j) {
                    float m = fmaxf(v[j], ev[j]);
                    m = fmaxf(m, __shfl_xor(m, 1));
                    unsigned short us = f2bf(m);
                    if (j & 1) pk[j >> 1] |= ((unsigned int)us) << 16;
                    else       pk[j >> 1]  = us;
                }
                if (!(n & 1)) {
                    int py = (cy0 >> 1) + (y >> 1), px = (cx0 >> 1) + (n >> 1);
                    unsigned short* dstp =
                        act2 + ((size_t)((b*56 + py)*56 + px))*OC + oc0w + quad*4;
                    *(uint2*)dstp = *(uint2*)pk;
                }
            }
        }
    }
}

// ---------------------------------------------------------------------------
// Kernel D: conv3 (64->128, 56x56) bf16 MFMA + bn + relu + spatial mean sum.
// (unchanged this round — surfaces in top-5 next round for counter evidence)
// ---------------------------------------------------------------------------
__global__ __launch_bounds__(256) void conv3_mfma(
    const unsigned short* __restrict__ act2,
    const unsigned short* __restrict__ wrep,
    const float* __restrict__ bn_s, const float* __restrict__ bn_t,
    float* __restrict__ feat)
{
    constexpr int IC = 64, OC = 128, H = 56;
    __shared__ __align__(16) short lds[8*18*18*8];

    const int tid = threadIdx.x;
    const int b = blockIdx.z >> 1, half = blockIdx.z & 1;
    const int cx0 = blockIdx.x*16, cy0 = blockIdx.y*16;
    const unsigned short* ab = act2 + (size_t)b*H*H*IC;

    for (int s = tid; s < 8*324; s += 256) {
        int ck = s / 324; int rem = s - ck*324;
        int y = rem / 18, xx = rem - y*18;
        int gy = cy0 - 1 + y, gx = cx0 - 1 + xx;
        uint4 v = {0,0,0,0};
        if ((unsigned)gy < H && (unsigned)gx < H)
            v = *(const uint4*)(ab + (size_t)(gy*H + gx)*IC + ck*8);
        *(uint4*)&lds[s*8] = v;
    }

    const int lane = tid & 63, wave = tid >> 6;
    const int n = lane & 15, quad = lane >> 4;
    const int oc0w = half*64 + wave*16;

    short8 afr[18];
#pragma unroll
    for (int t = 0; t < 9; ++t)
#pragma unroll
        for (int kc = 0; kc < 2; ++kc)
            afr[t*2 + kc] = *(const short8*)(wrep + (size_t)(t*OC + oc0w + n)*IC + kc*32 + quad*8);

    float4 sv = *(const float4*)(bn_s + oc0w + quad*4);
    float4 tv = *(const float4*)(bn_t + oc0w + quad*4);

    __syncthreads();

    float sum[4] = {0.f, 0.f, 0.f, 0.f};
    const bool vx = (cx0 + n) < H;
    const int ymax = (H - cy0) < 16 ? (H - cy0) : 16;
    float sj[4] = {sv.x, sv.y, sv.z, sv.w};
    float tj[4] = {tv.x, tv.y, tv.z, tv.w};

    for (int y = 0; y < ymax; ++y) {
        floatx4 acc0 = {0.f,0.f,0.f,0.f};
        floatx4 acc1 = {0.f,0.f,0.f,0.f};
#pragma unroll
        for (int ky = 0; ky < 3; ++ky)
#pragma unroll
            for (int kx = 0; kx < 3; ++kx) {
                int t = ky*3 + kx;
                short8 b0 = *(const short8*)&lds[(((0*4 + quad)*18 + y+ky)*18 + n+kx)*8];
                short8 b1 = *(const short8*)&lds[(((1*4 + quad)*18 + y+ky)*18 + n+kx)*8];
                acc0 = __builtin_amdgcn_mfma_f32_16x16x32_bf16(afr[t*2+0], b0, acc0, 0, 0, 0);
                acc1 = __builtin_amdgcn_mfma_f32_16x16x32_bf16(afr[t*2+1], b1, acc1, 0, 0, 0);
            }
        if (vx) {
#pragma unroll
            for (int j = 0; j < 4; ++j)
                sum[j] += fmaxf(fmaf(acc0[j] + acc1[j], sj[j], tj[j]), 0.f);
        }
    }
#pragma unroll
    for (int j = 0; j < 4; ++j) {
        sum[j] += __shfl_xor(sum[j], 1);
        sum[j] += __shfl_xor(sum[j], 2);
        sum[j] += __shfl_xor(sum[j], 4);
        sum[j] += __shfl_xor(sum[j], 8);
    }
    if (n == 0) {
#pragma unroll
        for (int j = 0; j < 4; ++j)
            atomicAdd(&feat[b*128 + oc0w + quad*4 + j], sum[j]);
    }
}

// ---------------------------------------------------------------------------
// Kernel E: FC head.
// ---------------------------------------------------------------------------
__global__ __launch_bounds__(256) void fc_kernel(
    const float* __restrict__ feat, const float* __restrict__ fc_w,
    const float* __restrict__ fc_b, float* __restrict__ out)
{
    int i = blockIdx.x * 256 + threadIdx.x;
    if (i >= BATCH*100) return;
    int b = i / 100, n = i - b*100;
    const float* f = feat + b*128;
    const float* w = fc_w + n*128;
    float s = 0.f;
#pragma unroll 4
    for (int k = 0; k < 128; ++k) s = fmaf(f[k], w[k], s);
    out[i] = s * (1.f/3136.f) + fc_b[n];
}

extern "C" void kernel_launch(void* const* d_in, const int* in_sizes, int n_in,
                              void* d_out, int out_size, void* d_ws, size_t ws_size,
                              hipStream_t stream)
{
    const float* x       = (const float*)d_in[0];
    const float* w1      = (const float*)d_in[1];
    const float* b1      = (const float*)d_in[2];
    const float* w2      = (const float*)d_in[3];
    const float* b2      = (const float*)d_in[4];
    const float* w3      = (const float*)d_in[5];
    const float* b3      = (const float*)d_in[6];
    const float* wb      = (const float*)d_in[7];
    const float* bb      = (const float*)d_in[8];
    const float* conv2_w = (const float*)d_in[9];
    const float* conv2_b = (const float*)d_in[10];
    const float* conv3_w = (const float*)d_in[11];
    const float* conv3_b = (const float*)d_in[12];
    const float* bn1_g = (const float*)d_in[13];
    const float* bn1_b = (const float*)d_in[14];
    const float* bn1_m = (const float*)d_in[15];
    const float* bn1_v = (const float*)d_in[16];
    const float* bn2_g = (const float*)d_in[17];
    const float* bn2_b = (const float*)d_in[18];
    const float* bn2_m = (const float*)d_in[19];
    const float* bn2_v = (const float*)d_in[20];
    const float* bn3_g = (const float*)d_in[21];
    const float* bn3_b = (const float*)d_in[22];
    const float* bn3_m = (const float*)d_in[23];
    const float* bn3_v = (const float*)d_in[24];
    const float* fc_w  = (const float*)d_in[25];
    const float* fc_b  = (const float*)d_in[26];
    float* out = (float*)d_out;

    char* wsb = (char*)d_ws;
    float* ws    = (float*)d_ws;
    float* dwt   = ws;                  // 864 f (transposed [tap][oc])
    float* bn1_s = ws + 864;
    float* bn1_t = ws + 896;
    float* bn2_s = ws + 928;
    float* bn2_t = ws + 992;
    float* bn3_s = ws + 1056;
    float* bn3_t = ws + 1184;
    float* feat  = ws + 1312;           // 4096 f
    unsigned short* wrep2 = (unsigned short*)(wsb + 32768);    // 18432 ush
    unsigned short* wrep3 = (unsigned short*)(wsb + 69632);    // 73728 ush
    unsigned short* act1  = (unsigned short*)(wsb + 262144);   // 25.7MB
    unsigned short* act2  = (unsigned short*)(wsb + 262144 + 25690112); // 12.8MB

    gen_small<<<1, 256, 0, stream>>>(
        wb, bb, conv2_b, conv3_b,
        bn1_g, bn1_b, bn1_m, bn1_v, bn2_g, bn2_b, bn2_m, bn2_v,
        bn3_g, bn3_b, bn3_m, bn3_v,
        bn1_s, bn1_t, bn2_s, bn2_t, bn3_s, bn3_t, feat);

    gen_dynw_repack<<<576, 256, 0, stream>>>(
        w1, b1, w2, b2, w3, b3, conv2_w, conv3_w, dwt, wrep2, wrep3);

    conv1_pool<<<dim3(7, 7, BATCH), 256, 0, stream>>>(
        x, dwt, bn1_s, bn1_t, act1);

    conv2_mfma<<<dim3(7, 7, BATCH), 256, 0, stream>>>(
        act1, wrep2, bn2_s, bn2_t, act2);

    conv3_mfma<<<dim3(4, 4, BATCH*2), 256, 0, stream>>>(
        act2, wrep3, bn3_s, bn3_t, feat);

    fc_kernel<<<(BATCH*100 + 255)/256, 256, 0, stream>>>(feat, fc_w, fc_b, out);
}